// Round 11
// baseline (23.968 us; speedup 1.0000x reference)
//
#include <hip/hip_runtime.h>

#define LSTREAM 512
#define C 8
#define OUTD 584    // 8 + 64 + 512
#define NW 16       // waves per block
#define SEG 32      // steps per wave (wave 15's step 511 is an exact no-op)
#define INCF 4096   // 512 rows x 8 floats (row 511 zeroed)
#define PSTRIDE 600 // partial-signature stride in floats

// compile-time-lane broadcast from the distributed row file (VALU pipe)
#define RDL(v, L) __int_as_float(__builtin_amdgcn_readlane(__float_as_int(v), (L)))

// Chen combine: state (a, in regs) <- a (x) b (in LDS at bp). a is earlier.
// Lane = i*8+j owns a2[i][j] (s2), a3[i][j][0..7] (s3); s1i = a1[i].
__device__ __forceinline__ void chen_combine(const float* bp, int i, int j, int lane,
                                             float& s1i, float& s2, float (&s3)[C]) {
    const float  b1i  = bp[i];
    const float  b1j  = bp[j];
    const float4 b1lo = *reinterpret_cast<const float4*>(bp);
    const float4 b1hi = *reinterpret_cast<const float4*>(bp + 4);
    const float4 b2lo = *reinterpret_cast<const float4*>(bp + C + j * C);
    const float4 b2hi = *reinterpret_cast<const float4*>(bp + C + j * C + 4);
    const float  b2ij = bp[C + lane];
    const float4 b3lo = *reinterpret_cast<const float4*>(bp + C + 64 + lane * C);
    const float4 b3hi = *reinterpret_cast<const float4*>(bp + C + 64 + lane * C + 4);
    const float b1k[C]  = {b1lo.x, b1lo.y, b1lo.z, b1lo.w, b1hi.x, b1hi.y, b1hi.z, b1hi.w};
    const float b2jk[C] = {b2lo.x, b2lo.y, b2lo.z, b2lo.w, b2hi.x, b2hi.y, b2hi.z, b2hi.w};
    const float b3k[C]  = {b3lo.x, b3lo.y, b3lo.z, b3lo.w, b3hi.x, b3hi.y, b3hi.z, b3hi.w};
    #pragma unroll
    for (int k = 0; k < C; ++k)
        s3[k] = s3[k] + b3k[k] + s1i * b2jk[k] + s2 * b1k[k];
    s2 = s2 + b2ij + s1i * b1j;
    s1i += b1i;
}

__device__ __forceinline__ void store_partial(float* pp, int i, int j, int lane,
                                              float s1i, float s2, const float (&s3)[C]) {
    if (j == 0) pp[i] = s1i;
    pp[C + lane] = s2;
    #pragma unroll
    for (int k = 0; k < C; ++k) pp[C + 64 + lane * C + k] = s3[k];
}

__global__ __launch_bounds__(1024, 4) void sig_kernel(const float* __restrict__ path,
                                                      float* __restrict__ out) {
    __shared__ float inc[INCF];            // 16 KB: increments, row 511 = 0
    __shared__ float part[NW * PSTRIDE];   // 37.5 KB: per-wave partials
    const int b    = blockIdx.x;
    const int tid  = threadIdx.x;
    const int wu   = tid >> 6;
    const int lane = tid & 63;
    const int i = lane >> 3;
    const int j = lane & 7;

    const float* pb = path + (size_t)b * (LSTREAM * C);

    // ---- pre-pass: increments -> LDS (coalesced float4); zero row 511 ----
    // also warms L1 for the row-file loads below
    {
        const int row = tid >> 1;
        float4 d = {0.f, 0.f, 0.f, 0.f};
        if (row < LSTREAM - 1) {
            const float4* p4 = reinterpret_cast<const float4*>(pb);
            const float4 a = p4[tid];
            const float4 c = p4[tid + 2];
            d.x = c.x - a.x; d.y = c.y - a.y; d.z = c.z - a.z; d.w = c.w - a.w;
        }
        reinterpret_cast<float4*>(inc)[tid] = d;
    }
    __syncthreads();

    const int r0 = wu * SEG;
    const float* pI = inc + r0 * C + i;    // per-lane dxi stream (8-way broadcast, conflict-free)
    const float* pJ = inc + r0 * C + j;

    // ---- distributed row file: rf[r] lane l = path flat [r0*8 + 64r + l] ----
    // rows r0..r0+31 in rf[0..3]; rf[4] lanes 0..7 = x[min(r0+32,511)][0..7]
    float rf[5];
    #pragma unroll
    for (int r = 0; r < 5; ++r) {
        int fi = r0 * C + 64 * r + lane;
        if (r == 4) fi = min(fi, (LSTREAM - 1) * C + (lane & 7));  // clamp (wave 15 only)
        rf[r] = pb[fi];
    }

    float s1i = 0.f, s2 = 0.f, cfp = 0.f;
    float s3[C];
    #pragma unroll
    for (int k = 0; k < C; ++k) s3[k] = 0.f;

    // summation by parts: s3 = sum_s (cf_{s-1} - cf_s) * x_{r0+s} + cf_last * x_end
    #pragma unroll
    for (int s = 0; s < SEG; ++s) {
        const float dxi = pI[s * C];
        const float dxj = pJ[s * C];
        const float u  = dxi * dxj;
        const float t1 = s1i * dxj;
        const float cf = fmaf(u, (1.f / 6.f), fmaf(t1, 0.5f, s2));
        const float w  = cfp - cf;
        // row x[r0+s][k] lives at lane ((s&7)*8+k) of rf[s>>3] -- VALU broadcast
        #pragma unroll
        for (int k = 0; k < C; ++k)
            s3[k] = fmaf(w, RDL(rf[s >> 3], ((s & 7) << 3) + k), s3[k]);
        s2 = fmaf(u, 0.5f, s2) + t1;
        s1i += dxi;
        cfp = cf;
    }
    // closing term: + cf_last * x_end (rf[4] lanes 0..7)
    #pragma unroll
    for (int k = 0; k < C; ++k) s3[k] = fmaf(cfp, RDL(rf[4], k), s3[k]);

    // ---- publish partials, tree-combine 16 -> 1 ----
    store_partial(part + wu * PSTRIDE, i, j, lane, s1i, s2, s3);
    __syncthreads();

    if ((wu & 1) == 0) chen_combine(part + (wu + 1) * PSTRIDE, i, j, lane, s1i, s2, s3);
    if (wu == 2 || wu == 6 || wu == 10 || wu == 14)
        store_partial(part + wu * PSTRIDE, i, j, lane, s1i, s2, s3);
    __syncthreads();

    if ((wu & 3) == 0) chen_combine(part + (wu + 2) * PSTRIDE, i, j, lane, s1i, s2, s3);
    if (wu == 4 || wu == 12)
        store_partial(part + wu * PSTRIDE, i, j, lane, s1i, s2, s3);
    __syncthreads();

    if ((wu & 7) == 0) chen_combine(part + (wu + 4) * PSTRIDE, i, j, lane, s1i, s2, s3);
    if (wu == 8)
        store_partial(part + wu * PSTRIDE, i, j, lane, s1i, s2, s3);
    __syncthreads();

    if (wu == 0) {
        chen_combine(part + 8 * PSTRIDE, i, j, lane, s1i, s2, s3);
        float* ob = out + (size_t)b * OUTD;
        const float s1out = __shfl(s1i, (lane << 3) & 63, 64);
        if (lane < C) ob[lane] = s1out;
        ob[C + lane] = s2;
        #pragma unroll
        for (int k = 0; k < C; ++k) ob[C + 64 + lane * C + k] = s3[k];
    }
}

extern "C" void kernel_launch(void* const* d_in, const int* in_sizes, int n_in,
                              void* d_out, int out_size, void* d_ws, size_t ws_size,
                              hipStream_t stream) {
    const float* path = (const float*)d_in[0];
    float* out = (float*)d_out;
    const int B = in_sizes[0] / (LSTREAM * C);
    sig_kernel<<<B, 1024, 0, stream>>>(path, out);
}